// Round 1
// baseline (625.421 us; speedup 1.0000x reference)
//
#include <hip/hip_runtime.h>

typedef unsigned short u16;
typedef __bf16 bf16x8 __attribute__((ext_vector_type(8)));
typedef float f32x4 __attribute__((ext_vector_type(4)));

#define S_LEN 2048
#define NHEADS 16
#define HD 64
#define HDIM 1024
#define QKVN 3072
#define KAUG 9216   // 1024 (silu) + 1024*8 (spline bases)

__device__ __forceinline__ u16 f2bf(float f) {
  union { float f; unsigned u; } v; v.f = f;
  unsigned r = v.u + 0x7fffu + ((v.u >> 16) & 1u);   // RNE
  return (u16)(r >> 16);
}

typedef __attribute__((address_space(1))) const unsigned int gas_u32;
typedef __attribute__((address_space(3))) unsigned int las_u32;
__device__ __forceinline__ void gload_lds16(const void* g, void* l) {
  __builtin_amdgcn_global_load_lds((gas_u32*)g, (las_u32*)l, 16, 0, 0);
}

// ---------------- prep A: silu(x) and cubic b-spline bases, bf16 ----------------
__global__ void prep_a_kernel(const float* __restrict__ x, u16* __restrict__ Aaug) {
  int idx = blockIdx.x * 256 + threadIdx.x;     // 2048*1024 threads
  int n = idx >> 10, i = idx & 1023;
  float xv = x[idx];
  float sil = xv / (1.0f + __expf(-xv));
  Aaug[(size_t)n * KAUG + i] = f2bf(sil);

  float b[11];
#pragma unroll
  for (int j = 0; j < 11; ++j) {
    float t0 = 0.4f * (float)(j - 3) - 1.0f;
    float t1 = 0.4f * (float)(j - 2) - 1.0f;
    b[j] = (xv >= t0 && xv < t1) ? 1.0f : 0.0f;
  }
#pragma unroll
  for (int k = 1; k <= 3; ++k) {
#pragma unroll
    for (int j = 0; j < 10; ++j) {
      if (j + k < 11) {
        float tj   = 0.4f * (float)(j - 3) - 1.0f;
        float tjk  = tj + 0.4f * (float)k;
        float tj1  = tj + 0.4f;
        float tjk1 = tjk + 0.4f;
        b[j] = (xv - tj) / (tjk - tj) * b[j] + (tjk1 - xv) / (tjk1 - tj1) * b[j + 1];
      }
    }
  }
  u16 t[8];
#pragma unroll
  for (int j = 0; j < 8; ++j) t[j] = f2bf(b[j]);
  uint4 pk;
  pk.x = (unsigned)t[0] | ((unsigned)t[1] << 16);
  pk.y = (unsigned)t[2] | ((unsigned)t[3] << 16);
  pk.z = (unsigned)t[4] | ((unsigned)t[5] << 16);
  pk.w = (unsigned)t[6] | ((unsigned)t[7] << 16);
  *reinterpret_cast<uint4*>(&Aaug[(size_t)n * KAUG + 1024 + i * 8]) = pk;
}

// ---------------- prep W: [base_w | spline_w*scaler] bf16 ----------------
__global__ void prep_w_kernel(const float* __restrict__ bw, const float* __restrict__ sw,
                              const float* __restrict__ sc, u16* __restrict__ Waug) {
  int idx = blockIdx.x * 256 + threadIdx.x;     // 3072*1024 threads
  int o = idx >> 10, i = idx & 1023;
  Waug[(size_t)o * KAUG + i] = f2bf(bw[idx]);
  float s = sc[idx];
  const float4* sp = reinterpret_cast<const float4*>(sw + (size_t)idx * 8);
  float4 a = sp[0], b = sp[1];
  uint4 pk;
  pk.x = (unsigned)f2bf(a.x * s) | ((unsigned)f2bf(a.y * s) << 16);
  pk.y = (unsigned)f2bf(a.z * s) | ((unsigned)f2bf(a.w * s) << 16);
  pk.z = (unsigned)f2bf(b.x * s) | ((unsigned)f2bf(b.y * s) << 16);
  pk.w = (unsigned)f2bf(b.z * s) | ((unsigned)f2bf(b.w * s) << 16);
  *reinterpret_cast<uint4*>(&Waug[(size_t)o * KAUG + 1024 + i * 8]) = pk;
}

// ---------------- prep out_w -> bf16 ----------------
__global__ void prep_ow_kernel(const float* __restrict__ ow, u16* __restrict__ owbf) {
  int idx = blockIdx.x * 256 + threadIdx.x;     // 1024*1024/4 threads
  float4 v = reinterpret_cast<const float4*>(ow)[idx];
  uint2 pk;
  pk.x = (unsigned)f2bf(v.x) | ((unsigned)f2bf(v.y) << 16);
  pk.y = (unsigned)f2bf(v.z) | ((unsigned)f2bf(v.w) << 16);
  reinterpret_cast<uint2*>(owbf)[idx] = pk;
}

// ---------------- GEMM: C[M,N] = A[M,K] * B[N,K]^T (+bias), bf16 MFMA ----------------
__global__ __launch_bounds__(256) void gemm_bt(
    const u16* __restrict__ A, const u16* __restrict__ B, float* __restrict__ C,
    int M, int N, int K, const float* __restrict__ bias)
{
  __shared__ u16 As[128 * 32];
  __shared__ u16 Bs[128 * 32];
  const int tid = threadIdx.x;
  const int lane = tid & 63;
  const int w = tid >> 6;
  const int wr = w >> 1, wc = w & 1;
  const int bm = blockIdx.y, bn = blockIdx.x;
  const int row0 = bm * 128, col0 = bn * 128;
  const int lr = lane & 15, lg = lane >> 4;

  f32x4 acc[4][4];
#pragma unroll
  for (int m = 0; m < 4; ++m)
#pragma unroll
    for (int n = 0; n < 4; ++n) acc[m][n] = (f32x4){0.f, 0.f, 0.f, 0.f};

  const int arow = tid >> 2;      // 0..63
  const int kch  = tid & 3;       // 0..3, 8 bf16 each

  for (int k0 = 0; k0 < K; k0 += 32) {
    const u16* ga0 = A + (size_t)(row0 + arow) * K + k0 + kch * 8;
    const u16* ga1 = ga0 + (size_t)64 * K;
    gload_lds16(ga0, &As[tid * 8]);
    gload_lds16(ga1, &As[2048 + tid * 8]);
    const u16* gb0 = B + (size_t)(col0 + arow) * K + k0 + kch * 8;
    const u16* gb1 = gb0 + (size_t)64 * K;
    gload_lds16(gb0, &Bs[tid * 8]);
    gload_lds16(gb1, &Bs[2048 + tid * 8]);
    __syncthreads();

    bf16x8 af[4], bf[4];
#pragma unroll
    for (int m = 0; m < 4; ++m) {
      int r = wr * 64 + m * 16 + lr;
      af[m] = *reinterpret_cast<const bf16x8*>(&As[r * 32 + lg * 8]);
    }
#pragma unroll
    for (int n = 0; n < 4; ++n) {
      int r = wc * 64 + n * 16 + lr;
      bf[n] = *reinterpret_cast<const bf16x8*>(&Bs[r * 32 + lg * 8]);
    }
#pragma unroll
    for (int m = 0; m < 4; ++m)
#pragma unroll
      for (int n = 0; n < 4; ++n)
        acc[m][n] = __builtin_amdgcn_mfma_f32_16x16x32_bf16(af[m], bf[n], acc[m][n], 0, 0, 0);
    __syncthreads();
  }

#pragma unroll
  for (int m = 0; m < 4; ++m) {
    int row = row0 + wr * 64 + m * 16 + lg * 4;
#pragma unroll
    for (int n = 0; n < 4; ++n) {
      int col = col0 + wc * 64 + n * 16 + lr;
      float bv = bias ? bias[col] : 0.f;
#pragma unroll
      for (int j = 0; j < 4; ++j)
        C[(size_t)(row + j) * N + col] = acc[m][n][j] + bv;
    }
  }
}

// ---------------- RoPE on q,k; write per-head bf16 (q scaled by 1/8) ----------------
__global__ void rope_kernel(const float* __restrict__ qkv, const float* __restrict__ rc,
                            const float* __restrict__ rs, u16* __restrict__ qro,
                            u16* __restrict__ kro) {
  int idx = blockIdx.x * 256 + threadIdx.x;   // 16*2048*32
  int h = idx >> 16;
  int rem = idx & 65535;
  int s = rem >> 5, i = rem & 31;
  const float* base = qkv + (size_t)s * QKVN + h * 192;
  float q0 = base[2 * i], q1 = base[2 * i + 1];
  float k0 = base[64 + 2 * i], k1 = base[64 + 2 * i + 1];
  float c = rc[s * 32 + i], sn = rs[s * 32 + i];
  size_t ob = ((size_t)(h * S_LEN + s)) * HD + 2 * i;
  qro[ob]     = f2bf((q0 * c - q1 * sn) * 0.125f);
  qro[ob + 1] = f2bf((q0 * sn + q1 * c) * 0.125f);
  kro[ob]     = f2bf(k0 * c - k1 * sn);
  kro[ob + 1] = f2bf(k0 * sn + k1 * c);
}

// ---------------- V transpose: vT[h][d][s] bf16 ----------------
__global__ void vtrans_kernel(const float* __restrict__ qkv, u16* __restrict__ vT) {
  __shared__ float tile[64][65];
  int h = blockIdx.x >> 5;
  int st = blockIdx.x & 31;
  int s0 = st * 64;
  int t = threadIdx.x;
  int r = t >> 2, c4 = t & 3;
  const float* src = qkv + (size_t)(s0 + r) * QKVN + h * 192 + 128 + c4 * 16;
#pragma unroll
  for (int z = 0; z < 4; ++z) {
    float4 v = *reinterpret_cast<const float4*>(src + z * 4);
    tile[r][c4 * 16 + z * 4 + 0] = v.x;
    tile[r][c4 * 16 + z * 4 + 1] = v.y;
    tile[r][c4 * 16 + z * 4 + 2] = v.z;
    tile[r][c4 * 16 + z * 4 + 3] = v.w;
  }
  __syncthreads();
  int d = t >> 2, sc = t & 3;
  u16* dst = vT + ((size_t)(h * 64 + d)) * S_LEN + s0 + sc * 16;
  unsigned wv[8];
#pragma unroll
  for (int z = 0; z < 8; ++z) {
    unsigned lo = f2bf(tile[sc * 16 + 2 * z][d]);
    unsigned hi = f2bf(tile[sc * 16 + 2 * z + 1][d]);
    wv[z] = lo | (hi << 16);
  }
  *reinterpret_cast<uint4*>(dst)     = make_uint4(wv[0], wv[1], wv[2], wv[3]);
  *reinterpret_cast<uint4*>(dst + 8) = make_uint4(wv[4], wv[5], wv[6], wv[7]);
}

// ---------------- flash attention: 4 waves/block, 16 q-rows/wave ----------------
__global__ __launch_bounds__(256) void attn_kernel(
    const u16* __restrict__ qro, const u16* __restrict__ kro,
    const u16* __restrict__ vT, u16* __restrict__ ctxb)
{
  __shared__ u16 plds[4][2][16 * 32];
  const int lane = threadIdx.x & 63;
  const int w = threadIdx.x >> 6;
  const int bid = blockIdx.x;            // 16 heads * 32
  const int h = bid >> 5;
  const int qt = (bid & 31) * 4 + w;     // 0..127
  const int lr = lane & 15, lg = lane >> 4;

  const u16* qbase = qro + ((size_t)(h * S_LEN + qt * 16 + lr)) * HD + lg * 8;
  bf16x8 qa0 = *reinterpret_cast<const bf16x8*>(qbase);
  bf16x8 qa1 = *reinterpret_cast<const bf16x8*>(qbase + 32);

  float mrow[4], lrow[4];
  f32x4 o[4];
#pragma unroll
  for (int j = 0; j < 4; ++j) { mrow[j] = -3.0e38f; lrow[j] = 0.f; }
#pragma unroll
  for (int n = 0; n < 4; ++n) o[n] = (f32x4){0.f, 0.f, 0.f, 0.f};

  for (int kt = 0; kt < 64; ++kt) {
    const int key0 = kt * 32;
    const u16* kb = kro + ((size_t)(h * S_LEN + key0 + lr)) * HD + lg * 8;
    bf16x8 k00 = *reinterpret_cast<const bf16x8*>(kb);
    bf16x8 k01 = *reinterpret_cast<const bf16x8*>(kb + 32);
    bf16x8 k10 = *reinterpret_cast<const bf16x8*>(kb + (size_t)16 * HD);
    bf16x8 k11 = *reinterpret_cast<const bf16x8*>(kb + (size_t)16 * HD + 32);

    f32x4 s0 = (f32x4){0.f, 0.f, 0.f, 0.f};
    f32x4 s1 = (f32x4){0.f, 0.f, 0.f, 0.f};
    s0 = __builtin_amdgcn_mfma_f32_16x16x32_bf16(qa0, k00, s0, 0, 0, 0);
    s0 = __builtin_amdgcn_mfma_f32_16x16x32_bf16(qa1, k01, s0, 0, 0, 0);
    s1 = __builtin_amdgcn_mfma_f32_16x16x32_bf16(qa0, k10, s1, 0, 0, 0);
    s1 = __builtin_amdgcn_mfma_f32_16x16x32_bf16(qa1, k11, s1, 0, 0, 0);

    float p0[4], p1[4], alpha[4];
#pragma unroll
    for (int j = 0; j < 4; ++j) {
      float v = fmaxf(s0[j], s1[j]);
      v = fmaxf(v, __shfl_xor(v, 1));
      v = fmaxf(v, __shfl_xor(v, 2));
      v = fmaxf(v, __shfl_xor(v, 4));
      v = fmaxf(v, __shfl_xor(v, 8));
      float mn = fmaxf(mrow[j], v);
      float al = __expf(mrow[j] - mn);
      float e0 = __expf(s0[j] - mn);
      float e1 = __expf(s1[j] - mn);
      float ts = e0 + e1;
      ts += __shfl_xor(ts, 1);
      ts += __shfl_xor(ts, 2);
      ts += __shfl_xor(ts, 4);
      ts += __shfl_xor(ts, 8);
      lrow[j] = lrow[j] * al + ts;
      mrow[j] = mn;
      alpha[j] = al;
      p0[j] = e0; p1[j] = e1;
    }
#pragma unroll
    for (int n = 0; n < 4; ++n) {
#pragma unroll
      for (int j = 0; j < 4; ++j) o[n][j] *= alpha[j];
    }

    u16* pb = &plds[w][kt & 1][0];
#pragma unroll
    for (int j = 0; j < 4; ++j) {
      pb[(lg * 4 + j) * 32 + lr]      = f2bf(p0[j]);
      pb[(lg * 4 + j) * 32 + 16 + lr] = f2bf(p1[j]);
    }
    __syncthreads();   // also orders the u16 stores vs bf16x8 load below

    bf16x8 pa = *reinterpret_cast<const bf16x8*>(&pb[lr * 32 + lg * 8]);
    const u16* vb = vT + ((size_t)(h * 64 + lr)) * S_LEN + key0 + lg * 8;
#pragma unroll
    for (int n = 0; n < 4; ++n) {
      bf16x8 vf = *reinterpret_cast<const bf16x8*>(vb + (size_t)(n * 16) * S_LEN);
      o[n] = __builtin_amdgcn_mfma_f32_16x16x32_bf16(pa, vf, o[n], 0, 0, 0);
    }
  }

#pragma unroll
  for (int n = 0; n < 4; ++n) {
    int col = h * 64 + n * 16 + lr;
#pragma unroll
    for (int j = 0; j < 4; ++j) {
      int row = qt * 16 + lg * 4 + j;
      ctxb[(size_t)row * HDIM + col] = f2bf(o[n][j] / lrow[j]);
    }
  }
}

extern "C" void kernel_launch(void* const* d_in, const int* in_sizes, int n_in,
                              void* d_out, int out_size, void* d_ws, size_t ws_size,
                              hipStream_t stream) {
  const float* x   = (const float*)d_in[0];
  const float* bw  = (const float*)d_in[1];
  const float* sw  = (const float*)d_in[2];
  const float* ssc = (const float*)d_in[3];
  const float* ow  = (const float*)d_in[4];
  const float* ob  = (const float*)d_in[5];
  const float* rc  = (const float*)d_in[6];
  const float* rs  = (const float*)d_in[7];
  float* out = (float*)d_out;

  char* ws = (char*)d_ws;
  u16*   Aaug = (u16*)(ws);                         // 2048*9216*2  = 37748736
  u16*   Waug = (u16*)(ws + 37748736);              // 3072*9216*2  = 56623104
  float* qkv  = (float*)(ws + 94371840);            // 2048*3072*4  = 25165824
  u16*   qro  = (u16*)(ws + 119537664);             // 16*2048*64*2 = 4194304
  u16*   kro  = (u16*)(ws + 123731968);             // 4194304
  u16*   vT   = (u16*)(ws + 127926272);             // 4194304
  u16*   ctxb = (u16*)(ws + 132120576);             // 2048*1024*2  = 4194304
  u16*   owbf = (u16*)(ws + 136314880);             // 1024*1024*2  = 2097152

  prep_a_kernel<<<8192, 256, 0, stream>>>(x, Aaug);
  prep_w_kernel<<<12288, 256, 0, stream>>>(bw, sw, ssc, Waug);
  prep_ow_kernel<<<1024, 256, 0, stream>>>(ow, owbf);

  gemm_bt<<<dim3(24, 16), 256, 0, stream>>>(Aaug, Waug, qkv, 2048, 3072, 9216, nullptr);

  rope_kernel<<<4096, 256, 0, stream>>>(qkv, rc, rs, qro, kro);
  vtrans_kernel<<<512, 256, 0, stream>>>(qkv, vT);

  attn_kernel<<<512, 256, 0, stream>>>(qro, kro, vT, ctxb);

  gemm_bt<<<dim3(8, 16), 256, 0, stream>>>(ctxb, owbf, out, 2048, 1024, 1024, ob);
}

// Round 3
// 539.037 us; speedup vs baseline: 1.1603x; 1.1603x over previous
//
#include <hip/hip_runtime.h>

typedef unsigned short u16;
typedef __bf16 bf16x8 __attribute__((ext_vector_type(8)));
typedef float f32x4 __attribute__((ext_vector_type(4)));

#define S_LEN 2048
#define NHEADS 16
#define HD 64
#define HDIM 1024
#define QKVN 3072
#define KAUG 9216   // 1024 (silu) + 1024*8 (spline bases)

__device__ __forceinline__ u16 f2bf(float f) {
  union { float f; unsigned u; } v; v.f = f;
  unsigned r = v.u + 0x7fffu + ((v.u >> 16) & 1u);   // RNE
  return (u16)(r >> 16);
}

typedef __attribute__((address_space(1))) const unsigned int gas_u32;
typedef __attribute__((address_space(3))) unsigned int las_u32;
__device__ __forceinline__ void gload_lds16(const void* g, void* l) {
  __builtin_amdgcn_global_load_lds((gas_u32*)g, (las_u32*)l, 16, 0, 0);
}

// ---------------- prep A: silu(x) and cubic b-spline bases, bf16 ----------------
__global__ void prep_a_kernel(const float* __restrict__ x, u16* __restrict__ Aaug) {
  int idx = blockIdx.x * 256 + threadIdx.x;     // 2048*1024 threads
  int n = idx >> 10, i = idx & 1023;
  float xv = x[idx];
  float sil = xv / (1.0f + __expf(-xv));
  Aaug[(size_t)n * KAUG + i] = f2bf(sil);

  float b[11];
#pragma unroll
  for (int j = 0; j < 11; ++j) {
    float t0 = 0.4f * (float)(j - 3) - 1.0f;
    float t1 = 0.4f * (float)(j - 2) - 1.0f;
    b[j] = (xv >= t0 && xv < t1) ? 1.0f : 0.0f;
  }
#pragma unroll
  for (int k = 1; k <= 3; ++k) {
#pragma unroll
    for (int j = 0; j < 10; ++j) {
      if (j + k < 11) {
        float tj   = 0.4f * (float)(j - 3) - 1.0f;
        float tjk  = tj + 0.4f * (float)k;
        float tj1  = tj + 0.4f;
        float tjk1 = tjk + 0.4f;
        b[j] = (xv - tj) / (tjk - tj) * b[j] + (tjk1 - xv) / (tjk1 - tj1) * b[j + 1];
      }
    }
  }
  u16 t[8];
#pragma unroll
  for (int j = 0; j < 8; ++j) t[j] = f2bf(b[j]);
  uint4 pk;
  pk.x = (unsigned)t[0] | ((unsigned)t[1] << 16);
  pk.y = (unsigned)t[2] | ((unsigned)t[3] << 16);
  pk.z = (unsigned)t[4] | ((unsigned)t[5] << 16);
  pk.w = (unsigned)t[6] | ((unsigned)t[7] << 16);
  *reinterpret_cast<uint4*>(&Aaug[(size_t)n * KAUG + 1024 + i * 8]) = pk;
}

// ---------------- prep W: [base_w | spline_w*scaler] bf16 ----------------
__global__ void prep_w_kernel(const float* __restrict__ bw, const float* __restrict__ sw,
                              const float* __restrict__ sc, u16* __restrict__ Waug) {
  int idx = blockIdx.x * 256 + threadIdx.x;     // 3072*1024 threads
  int o = idx >> 10, i = idx & 1023;
  Waug[(size_t)o * KAUG + i] = f2bf(bw[idx]);
  float s = sc[idx];
  const float4* sp = reinterpret_cast<const float4*>(sw + (size_t)idx * 8);
  float4 a = sp[0], b = sp[1];
  uint4 pk;
  pk.x = (unsigned)f2bf(a.x * s) | ((unsigned)f2bf(a.y * s) << 16);
  pk.y = (unsigned)f2bf(a.z * s) | ((unsigned)f2bf(a.w * s) << 16);
  pk.z = (unsigned)f2bf(b.x * s) | ((unsigned)f2bf(b.y * s) << 16);
  pk.w = (unsigned)f2bf(b.z * s) | ((unsigned)f2bf(b.w * s) << 16);
  *reinterpret_cast<uint4*>(&Waug[(size_t)o * KAUG + 1024 + i * 8]) = pk;
}

// ---------------- prep out_w -> bf16 ----------------
__global__ void prep_ow_kernel(const float* __restrict__ ow, u16* __restrict__ owbf) {
  int idx = blockIdx.x * 256 + threadIdx.x;     // 1024*1024/4 threads
  float4 v = reinterpret_cast<const float4*>(ow)[idx];
  uint2 pk;
  pk.x = (unsigned)f2bf(v.x) | ((unsigned)f2bf(v.y) << 16);
  pk.y = (unsigned)f2bf(v.z) | ((unsigned)f2bf(v.w) << 16);
  reinterpret_cast<uint2*>(owbf)[idx] = pk;
}

// ---------- GEMM: C[z][M,N] = A[M, kz] * B[N, kz]^T (+bias), bf16 MFMA, split-K via z ----------
__global__ __launch_bounds__(256) void gemm_bt(
    const u16* __restrict__ A, const u16* __restrict__ B, float* __restrict__ C,
    int M, int N, int K, int Ksp, const float* __restrict__ bias)
{
  __shared__ u16 As[128 * 32];
  __shared__ u16 Bs[128 * 32];
  const int tid = threadIdx.x;
  const int lane = tid & 63;
  const int w = tid >> 6;
  const int wr = w >> 1, wc = w & 1;
  const int bm = blockIdx.y, bn = blockIdx.x;
  const int row0 = bm * 128, col0 = bn * 128;
  const int lr = lane & 15, lg = lane >> 4;
  const int kbeg = blockIdx.z * Ksp;
  const int kend = kbeg + Ksp;
  float* Cz = C + (size_t)blockIdx.z * M * N;

  f32x4 acc[4][4];
#pragma unroll
  for (int m = 0; m < 4; ++m)
#pragma unroll
    for (int n = 0; n < 4; ++n) acc[m][n] = (f32x4){0.f, 0.f, 0.f, 0.f};

  const int arow = tid >> 2;      // 0..63
  const int kch  = tid & 3;       // 0..3, 8 bf16 each

  for (int k0 = kbeg; k0 < kend; k0 += 32) {
    const u16* ga0 = A + (size_t)(row0 + arow) * K + k0 + kch * 8;
    const u16* ga1 = ga0 + (size_t)64 * K;
    gload_lds16(ga0, &As[tid * 8]);
    gload_lds16(ga1, &As[2048 + tid * 8]);
    const u16* gb0 = B + (size_t)(col0 + arow) * K + k0 + kch * 8;
    const u16* gb1 = gb0 + (size_t)64 * K;
    gload_lds16(gb0, &Bs[tid * 8]);
    gload_lds16(gb1, &Bs[2048 + tid * 8]);
    __syncthreads();

    bf16x8 af[4], bf[4];
#pragma unroll
    for (int m = 0; m < 4; ++m) {
      int r = wr * 64 + m * 16 + lr;
      af[m] = *reinterpret_cast<const bf16x8*>(&As[r * 32 + lg * 8]);
    }
#pragma unroll
    for (int n = 0; n < 4; ++n) {
      int r = wc * 64 + n * 16 + lr;
      bf[n] = *reinterpret_cast<const bf16x8*>(&Bs[r * 32 + lg * 8]);
    }
#pragma unroll
    for (int m = 0; m < 4; ++m)
#pragma unroll
      for (int n = 0; n < 4; ++n)
        acc[m][n] = __builtin_amdgcn_mfma_f32_16x16x32_bf16(af[m], bf[n], acc[m][n], 0, 0, 0);
    __syncthreads();
  }

#pragma unroll
  for (int m = 0; m < 4; ++m) {
    int row = row0 + wr * 64 + m * 16 + lg * 4;
#pragma unroll
    for (int n = 0; n < 4; ++n) {
      int col = col0 + wc * 64 + n * 16 + lr;
      float bv = bias ? bias[col] : 0.f;
#pragma unroll
      for (int j = 0; j < 4; ++j)
        Cz[(size_t)(row + j) * N + col] = acc[m][n][j] + bv;
    }
  }
}

// ------- RoPE on q,k (sums the 2 split-K partials); per-head bf16, q scaled 1/8 -------
__global__ void rope_kernel(const float* __restrict__ qkv0, const float* __restrict__ qkv1,
                            const float* __restrict__ rc, const float* __restrict__ rs,
                            u16* __restrict__ qro, u16* __restrict__ kro) {
  int idx = blockIdx.x * 256 + threadIdx.x;   // 16*2048*32
  int h = idx >> 16;
  int rem = idx & 65535;
  int s = rem >> 5, i = rem & 31;
  size_t boff = (size_t)s * QKVN + h * 192;
  const float* b0 = qkv0 + boff;
  const float* b1 = qkv1 + boff;
  float q0 = b0[2 * i] + b1[2 * i];
  float q1 = b0[2 * i + 1] + b1[2 * i + 1];
  float k0 = b0[64 + 2 * i] + b1[64 + 2 * i];
  float k1 = b0[64 + 2 * i + 1] + b1[64 + 2 * i + 1];
  float c = rc[s * 32 + i], sn = rs[s * 32 + i];
  size_t ob = ((size_t)(h * S_LEN + s)) * HD + 2 * i;
  qro[ob]     = f2bf((q0 * c - q1 * sn) * 0.125f);
  qro[ob + 1] = f2bf((q0 * sn + q1 * c) * 0.125f);
  kro[ob]     = f2bf(k0 * c - k1 * sn);
  kro[ob + 1] = f2bf(k0 * sn + k1 * c);
}

// ---------------- V transpose (sums 2 partials): vT[h][d][s] bf16 ----------------
__global__ void vtrans_kernel(const float* __restrict__ qkv0, const float* __restrict__ qkv1,
                              u16* __restrict__ vT) {
  __shared__ float tile[64][65];
  int h = blockIdx.x >> 5;
  int st = blockIdx.x & 31;
  int s0 = st * 64;
  int t = threadIdx.x;
  int r = t >> 2, c4 = t & 3;
  size_t soff = (size_t)(s0 + r) * QKVN + h * 192 + 128 + c4 * 16;
  const float* src0 = qkv0 + soff;
  const float* src1 = qkv1 + soff;
#pragma unroll
  for (int z = 0; z < 4; ++z) {
    float4 v = *reinterpret_cast<const float4*>(src0 + z * 4);
    float4 u = *reinterpret_cast<const float4*>(src1 + z * 4);
    tile[r][c4 * 16 + z * 4 + 0] = v.x + u.x;
    tile[r][c4 * 16 + z * 4 + 1] = v.y + u.y;
    tile[r][c4 * 16 + z * 4 + 2] = v.z + u.z;
    tile[r][c4 * 16 + z * 4 + 3] = v.w + u.w;
  }
  __syncthreads();
  int d = t >> 2, sc = t & 3;
  u16* dst = vT + ((size_t)(h * 64 + d)) * S_LEN + s0 + sc * 16;
  unsigned wv[8];
#pragma unroll
  for (int z = 0; z < 8; ++z) {
    unsigned lo = f2bf(tile[sc * 16 + 2 * z][d]);
    unsigned hi = f2bf(tile[sc * 16 + 2 * z + 1][d]);
    wv[z] = lo | (hi << 16);
  }
  *reinterpret_cast<uint4*>(dst)     = make_uint4(wv[0], wv[1], wv[2], wv[3]);
  *reinterpret_cast<uint4*>(dst + 8) = make_uint4(wv[4], wv[5], wv[6], wv[7]);
}

// ---------------- flash attention: 4 waves/block, 16 q-rows/wave, no block barriers ----------------
__global__ __launch_bounds__(256) void attn_kernel(
    const u16* __restrict__ qro, const u16* __restrict__ kro,
    const u16* __restrict__ vT, u16* __restrict__ ctxb)
{
  __shared__ u16 plds[4][2][16 * 32];
  const int lane = threadIdx.x & 63;
  const int w = threadIdx.x >> 6;
  const int bid = blockIdx.x;            // 16 heads * 32
  const int h = bid >> 5;
  const int qt = (bid & 31) * 4 + w;     // 0..127
  const int lr = lane & 15, lg = lane >> 4;

  const u16* qbase = qro + ((size_t)(h * S_LEN + qt * 16 + lr)) * HD + lg * 8;
  bf16x8 qa0 = *reinterpret_cast<const bf16x8*>(qbase);
  bf16x8 qa1 = *reinterpret_cast<const bf16x8*>(qbase + 32);

  float mrow[4], lrow[4];
  f32x4 o[4];
#pragma unroll
  for (int j = 0; j < 4; ++j) { mrow[j] = -3.0e38f; lrow[j] = 0.f; }
#pragma unroll
  for (int n = 0; n < 4; ++n) o[n] = (f32x4){0.f, 0.f, 0.f, 0.f};

  for (int kt = 0; kt < 64; ++kt) {
    const int key0 = kt * 32;
    const u16* kb = kro + ((size_t)(h * S_LEN + key0 + lr)) * HD + lg * 8;
    bf16x8 k00 = *reinterpret_cast<const bf16x8*>(kb);
    bf16x8 k01 = *reinterpret_cast<const bf16x8*>(kb + 32);
    bf16x8 k10 = *reinterpret_cast<const bf16x8*>(kb + (size_t)16 * HD);
    bf16x8 k11 = *reinterpret_cast<const bf16x8*>(kb + (size_t)16 * HD + 32);

    f32x4 s0 = (f32x4){0.f, 0.f, 0.f, 0.f};
    f32x4 s1 = (f32x4){0.f, 0.f, 0.f, 0.f};
    s0 = __builtin_amdgcn_mfma_f32_16x16x32_bf16(qa0, k00, s0, 0, 0, 0);
    s0 = __builtin_amdgcn_mfma_f32_16x16x32_bf16(qa1, k01, s0, 0, 0, 0);
    s1 = __builtin_amdgcn_mfma_f32_16x16x32_bf16(qa0, k10, s1, 0, 0, 0);
    s1 = __builtin_amdgcn_mfma_f32_16x16x32_bf16(qa1, k11, s1, 0, 0, 0);

    // online softmax: max is reduced across the 16-lane row-group; the
    // denominator stays a per-lane partial (alpha is row-uniform) and is
    // reduced once after the loop.
    float p0[4], p1[4], alpha[4];
#pragma unroll
    for (int j = 0; j < 4; ++j) {
      float v = fmaxf(s0[j], s1[j]);
      v = fmaxf(v, __shfl_xor(v, 1));
      v = fmaxf(v, __shfl_xor(v, 2));
      v = fmaxf(v, __shfl_xor(v, 4));
      v = fmaxf(v, __shfl_xor(v, 8));
      float mn = fmaxf(mrow[j], v);
      float al = __expf(mrow[j] - mn);
      float e0 = __expf(s0[j] - mn);
      float e1 = __expf(s1[j] - mn);
      lrow[j] = lrow[j] * al + e0 + e1;
      mrow[j] = mn;
      alpha[j] = al;
      p0[j] = e0; p1[j] = e1;
    }
#pragma unroll
    for (int n = 0; n < 4; ++n) {
#pragma unroll
      for (int j = 0; j < 4; ++j) o[n][j] *= alpha[j];
    }

    // per-wave private LDS round trip: wave-internal lgkmcnt ordering only,
    // no block barrier needed (each wave owns plds[w]).
    u16* pb = &plds[w][kt & 1][0];
#pragma unroll
    for (int j = 0; j < 4; ++j) {
      pb[(lg * 4 + j) * 32 + lr]      = f2bf(p0[j]);
      pb[(lg * 4 + j) * 32 + 16 + lr] = f2bf(p1[j]);
    }

    bf16x8 pa = *reinterpret_cast<const bf16x8*>(&pb[lr * 32 + lg * 8]);
    const u16* vb = vT + ((size_t)(h * 64 + lr)) * S_LEN + key0 + lg * 8;
#pragma unroll
    for (int n = 0; n < 4; ++n) {
      bf16x8 vf = *reinterpret_cast<const bf16x8*>(vb + (size_t)(n * 16) * S_LEN);
      o[n] = __builtin_amdgcn_mfma_f32_16x16x32_bf16(pa, vf, o[n], 0, 0, 0);
    }
  }

#pragma unroll
  for (int j = 0; j < 4; ++j) {
    float t = lrow[j];
    t += __shfl_xor(t, 1);
    t += __shfl_xor(t, 2);
    t += __shfl_xor(t, 4);
    t += __shfl_xor(t, 8);
    lrow[j] = t;
  }

#pragma unroll
  for (int n = 0; n < 4; ++n) {
    int col = h * 64 + n * 16 + lr;
#pragma unroll
    for (int j = 0; j < 4; ++j) {
      int row = qt * 16 + lg * 4 + j;
      ctxb[(size_t)row * HDIM + col] = f2bf(o[n][j] / lrow[j]);
    }
  }
}

extern "C" void kernel_launch(void* const* d_in, const int* in_sizes, int n_in,
                              void* d_out, int out_size, void* d_ws, size_t ws_size,
                              hipStream_t stream) {
  const float* x   = (const float*)d_in[0];
  const float* bw  = (const float*)d_in[1];
  const float* sw  = (const float*)d_in[2];
  const float* ssc = (const float*)d_in[3];
  const float* ow  = (const float*)d_in[4];
  const float* ob  = (const float*)d_in[5];
  const float* rc  = (const float*)d_in[6];
  const float* rs  = (const float*)d_in[7];
  float* out = (float*)d_out;

  char* ws = (char*)d_ws;
  u16*   Aaug  = (u16*)(ws);                        // 2048*9216*2  = 37,748,736
  u16*   Waug  = (u16*)(ws + 37748736);             // 3072*9216*2  = 56,623,104
  float* qkv0  = (float*)(ws + 94371840);           // 2048*3072*4  = 25,165,824
  float* qkv1  = (float*)(ws + 119537664);          // 25,165,824
  u16*   qro   = (u16*)(ws + 144703488);            // 16*2048*64*2 = 4,194,304
  u16*   kro   = (u16*)(ws + 148897792);            // 4,194,304
  u16*   vT    = (u16*)(ws + 153092096);            // 4,194,304
  u16*   owbf  = (u16*)(ws + 157286400);            // 1024*1024*2  = 2,097,152
  u16*   ctxb  = (u16*)(ws + 94371840);             // aliases qkv0 (dead after vtrans)

  prep_a_kernel<<<8192, 256, 0, stream>>>(x, Aaug);
  prep_w_kernel<<<12288, 256, 0, stream>>>(bw, sw, ssc, Waug);
  prep_ow_kernel<<<1024, 256, 0, stream>>>(ow, owbf);

  // split-K=2: 768 blocks -> ~3 waves/SIMD resident
  gemm_bt<<<dim3(24, 16, 2), 256, 0, stream>>>(Aaug, Waug, qkv0, 2048, 3072, 9216, 4608, nullptr);

  rope_kernel<<<4096, 256, 0, stream>>>(qkv0, qkv1, rc, rs, qro, kro);
  vtrans_kernel<<<512, 256, 0, stream>>>(qkv0, qkv1, vT);

  attn_kernel<<<512, 256, 0, stream>>>(qro, kro, vT, ctxb);

  gemm_bt<<<dim3(8, 16, 1), 256, 0, stream>>>(ctxb, owbf, out, 2048, 1024, 1024, 1024, ob);
}

// Round 4
// 529.767 us; speedup vs baseline: 1.1806x; 1.0175x over previous
//
#include <hip/hip_runtime.h>

typedef unsigned short u16;
typedef __bf16 bf16x8 __attribute__((ext_vector_type(8)));
typedef float f32x4 __attribute__((ext_vector_type(4)));

#define S_LEN 2048
#define NHEADS 16
#define HD 64
#define HDIM 1024
#define QKVN 3072
#define KAUG 9216   // 1024 (silu) + 1024*8 (spline bases)

__device__ __forceinline__ u16 f2bf(float f) {
  union { float f; unsigned u; } v; v.f = f;
  unsigned r = v.u + 0x7fffu + ((v.u >> 16) & 1u);   // RNE
  return (u16)(r >> 16);
}

typedef __attribute__((address_space(1))) const unsigned int gas_u32;
typedef __attribute__((address_space(3))) unsigned int las_u32;
__device__ __forceinline__ void gload_lds16(const void* g, void* l) {
  __builtin_amdgcn_global_load_lds((gas_u32*)g, (las_u32*)l, 16, 0, 0);
}

// ---------------- prep A: silu(x) and cubic b-spline bases, bf16 ----------------
__global__ void prep_a_kernel(const float* __restrict__ x, u16* __restrict__ Aaug) {
  int idx = blockIdx.x * 256 + threadIdx.x;     // 2048*1024 threads
  int n = idx >> 10, i = idx & 1023;
  float xv = x[idx];
  float sil = xv / (1.0f + __expf(-xv));
  Aaug[(size_t)n * KAUG + i] = f2bf(sil);

  float b[11];
#pragma unroll
  for (int j = 0; j < 11; ++j) {
    float t0 = 0.4f * (float)(j - 3) - 1.0f;
    float t1 = 0.4f * (float)(j - 2) - 1.0f;
    b[j] = (xv >= t0 && xv < t1) ? 1.0f : 0.0f;
  }
  // recurrence with constant reciprocals (denominators are 0.4*k): no fdiv
#pragma unroll
  for (int k = 1; k <= 3; ++k) {
    const float invk = (k == 1) ? 2.5f : (k == 2) ? 1.25f : 0.83333333f;
#pragma unroll
    for (int j = 0; j < 10; ++j) {
      if (j + k < 11) {
        float tj   = 0.4f * (float)(j - 3) - 1.0f;
        float tjk1 = 0.4f * (float)(j + k - 2) - 1.0f;
        b[j] = ((xv - tj) * b[j] + (tjk1 - xv) * b[j + 1]) * invk;
      }
    }
  }
  u16 t[8];
#pragma unroll
  for (int j = 0; j < 8; ++j) t[j] = f2bf(b[j]);
  uint4 pk;
  pk.x = (unsigned)t[0] | ((unsigned)t[1] << 16);
  pk.y = (unsigned)t[2] | ((unsigned)t[3] << 16);
  pk.z = (unsigned)t[4] | ((unsigned)t[5] << 16);
  pk.w = (unsigned)t[6] | ((unsigned)t[7] << 16);
  *reinterpret_cast<uint4*>(&Aaug[(size_t)n * KAUG + 1024 + i * 8]) = pk;
}

// ---------------- prep W: [base_w | spline_w*scaler] bf16 ----------------
__global__ void prep_w_kernel(const float* __restrict__ bw, const float* __restrict__ sw,
                              const float* __restrict__ sc, u16* __restrict__ Waug) {
  int idx = blockIdx.x * 256 + threadIdx.x;     // 3072*1024 threads
  int o = idx >> 10, i = idx & 1023;
  Waug[(size_t)o * KAUG + i] = f2bf(bw[idx]);
  float s = sc[idx];
  const float4* sp = reinterpret_cast<const float4*>(sw + (size_t)idx * 8);
  float4 a = sp[0], b = sp[1];
  uint4 pk;
  pk.x = (unsigned)f2bf(a.x * s) | ((unsigned)f2bf(a.y * s) << 16);
  pk.y = (unsigned)f2bf(a.z * s) | ((unsigned)f2bf(a.w * s) << 16);
  pk.z = (unsigned)f2bf(b.x * s) | ((unsigned)f2bf(b.y * s) << 16);
  pk.w = (unsigned)f2bf(b.z * s) | ((unsigned)f2bf(b.w * s) << 16);
  *reinterpret_cast<uint4*>(&Waug[(size_t)o * KAUG + 1024 + i * 8]) = pk;
}

// ---------------- prep out_w -> bf16 ----------------
__global__ void prep_ow_kernel(const float* __restrict__ ow, u16* __restrict__ owbf) {
  int idx = blockIdx.x * 256 + threadIdx.x;     // 1024*1024/4 threads
  float4 v = reinterpret_cast<const float4*>(ow)[idx];
  uint2 pk;
  pk.x = (unsigned)f2bf(v.x) | ((unsigned)f2bf(v.y) << 16);
  pk.y = (unsigned)f2bf(v.z) | ((unsigned)f2bf(v.w) << 16);
  reinterpret_cast<uint2*>(owbf)[idx] = pk;
}

// ---------- GEMM: C[z][M,N] = A[M, kz] * B[N, kz]^T, bf16 MFMA, BK=64, T2 swizzle ----------
// LDS layout: 16B chunks, element chunk (r, c8) stored at chunk index r*8 + (c8 ^ (r&7)).
// Staging keeps LDS dest linear (required by global_load_lds) and pre-swizzles the
// per-lane GLOBAL source chunk; ds_read applies the same XOR (rule #21).
__global__ __launch_bounds__(256) void gemm_bt(
    const u16* __restrict__ A, const u16* __restrict__ B, float* __restrict__ C,
    int M, int N, int K, int Ksp)
{
  __shared__ u16 As[128 * 64];
  __shared__ u16 Bs[128 * 64];
  const int tid = threadIdx.x;
  const int lane = tid & 63;
  const int w = tid >> 6;
  const int wr = w >> 1, wc = w & 1;
  const int row0 = blockIdx.y * 128, col0 = blockIdx.x * 128;
  const int lr = lane & 15, lg = lane >> 4;
  const int kbeg = blockIdx.z * Ksp;
  const int nsteps = Ksp >> 6;
  float* Cz = C + (size_t)blockIdx.z * M * N;

  f32x4 acc[4][4];
#pragma unroll
  for (int m = 0; m < 4; ++m)
#pragma unroll
    for (int n = 0; n < 4; ++n) acc[m][n] = (f32x4){0.f, 0.f, 0.f, 0.f};

  const int srow = tid >> 3;                    // 0..31
  const int c8sw = (tid & 7) ^ (srow & 7);      // pre-swizzled source chunk
  const u16* ga = A + (size_t)(row0 + srow) * K + kbeg + c8sw * 8;
  const u16* gb = B + (size_t)(col0 + srow) * K + kbeg + c8sw * 8;
  const size_t rstep = (size_t)32 * K;
  const int xr = lr & 7;                        // read-side XOR (r&7 == lr&7)

  for (int ks = 0; ks < nsteps; ++ks) {
#pragma unroll
    for (int i = 0; i < 4; ++i) {
      gload_lds16(ga + i * rstep, &As[i * 2048 + tid * 8]);
      gload_lds16(gb + i * rstep, &Bs[i * 2048 + tid * 8]);
    }
    ga += 64; gb += 64;
    __syncthreads();

#pragma unroll
    for (int kk = 0; kk < 2; ++kk) {
      bf16x8 af[4], bf[4];
#pragma unroll
      for (int m = 0; m < 4; ++m) {
        int r = wr * 64 + m * 16 + lr;
        int ch = (kk * 4 + lg) ^ xr;
        af[m] = *reinterpret_cast<const bf16x8*>(&As[r * 64 + ch * 8]);
      }
#pragma unroll
      for (int n = 0; n < 4; ++n) {
        int r = wc * 64 + n * 16 + lr;
        int ch = (kk * 4 + lg) ^ xr;
        bf[n] = *reinterpret_cast<const bf16x8*>(&Bs[r * 64 + ch * 8]);
      }
#pragma unroll
      for (int m = 0; m < 4; ++m)
#pragma unroll
        for (int n = 0; n < 4; ++n)
          acc[m][n] = __builtin_amdgcn_mfma_f32_16x16x32_bf16(af[m], bf[n], acc[m][n], 0, 0, 0);
    }
    __syncthreads();
  }

#pragma unroll
  for (int m = 0; m < 4; ++m) {
    int row = row0 + wr * 64 + m * 16 + lg * 4;
#pragma unroll
    for (int n = 0; n < 4; ++n) {
      int col = col0 + wc * 64 + n * 16 + lr;
#pragma unroll
      for (int j = 0; j < 4; ++j)
        Cz[(size_t)(row + j) * N + col] = acc[m][n][j];
    }
  }
}

// ---------------- reduce 4 split-K partials + bias (float4) ----------------
__global__ void reduce4_bias_kernel(const float* __restrict__ p, const float* __restrict__ bias,
                                    float* __restrict__ out) {
  int idx = blockIdx.x * 256 + threadIdx.x;     // 2048*1024/4
  const float4* p4 = reinterpret_cast<const float4*>(p);
  const size_t stride4 = (size_t)2048 * 1024 / 4;
  float4 a = p4[idx], b = p4[idx + stride4], c = p4[idx + 2 * stride4], d = p4[idx + 3 * stride4];
  float4 bv = reinterpret_cast<const float4*>(bias)[idx & 255];
  float4 r;
  r.x = a.x + b.x + c.x + d.x + bv.x;
  r.y = a.y + b.y + c.y + d.y + bv.y;
  r.z = a.z + b.z + c.z + d.z + bv.z;
  r.w = a.w + b.w + c.w + d.w + bv.w;
  reinterpret_cast<float4*>(out)[idx] = r;
}

// ------- RoPE on q,k (sums the 2 split-K partials); per-head bf16, q scaled 1/8 -------
__global__ void rope_kernel(const float* __restrict__ qkv0, const float* __restrict__ qkv1,
                            const float* __restrict__ rc, const float* __restrict__ rs,
                            u16* __restrict__ qro, u16* __restrict__ kro) {
  int idx = blockIdx.x * 256 + threadIdx.x;   // 16*2048*32
  int h = idx >> 16;
  int rem = idx & 65535;
  int s = rem >> 5, i = rem & 31;
  size_t boff = (size_t)s * QKVN + h * 192 + 2 * i;
  float2 q0v = *reinterpret_cast<const float2*>(qkv0 + boff);
  float2 q1v = *reinterpret_cast<const float2*>(qkv1 + boff);
  float2 k0v = *reinterpret_cast<const float2*>(qkv0 + boff + 64);
  float2 k1v = *reinterpret_cast<const float2*>(qkv1 + boff + 64);
  float q0 = q0v.x + q1v.x, q1 = q0v.y + q1v.y;
  float k0 = k0v.x + k1v.x, k1 = k0v.y + k1v.y;
  float c = rc[s * 32 + i], sn = rs[s * 32 + i];
  size_t ob = ((size_t)(h * S_LEN + s)) * HD + 2 * i;
  unsigned qpk = (unsigned)f2bf((q0 * c - q1 * sn) * 0.125f) |
                 ((unsigned)f2bf((q0 * sn + q1 * c) * 0.125f) << 16);
  unsigned kpk = (unsigned)f2bf(k0 * c - k1 * sn) |
                 ((unsigned)f2bf(k0 * sn + k1 * c) << 16);
  *reinterpret_cast<unsigned*>(qro + ob) = qpk;
  *reinterpret_cast<unsigned*>(kro + ob) = kpk;
}

// ---------------- V transpose (sums 2 partials): vT[h][d][s] bf16 ----------------
__global__ void vtrans_kernel(const float* __restrict__ qkv0, const float* __restrict__ qkv1,
                              u16* __restrict__ vT) {
  __shared__ float tile[64][65];
  int h = blockIdx.x >> 5;
  int st = blockIdx.x & 31;
  int s0 = st * 64;
  int t = threadIdx.x;
  int r = t >> 2, c4 = t & 3;
  size_t soff = (size_t)(s0 + r) * QKVN + h * 192 + 128 + c4 * 16;
  const float* src0 = qkv0 + soff;
  const float* src1 = qkv1 + soff;
#pragma unroll
  for (int z = 0; z < 4; ++z) {
    float4 v = *reinterpret_cast<const float4*>(src0 + z * 4);
    float4 u = *reinterpret_cast<const float4*>(src1 + z * 4);
    tile[r][c4 * 16 + z * 4 + 0] = v.x + u.x;
    tile[r][c4 * 16 + z * 4 + 1] = v.y + u.y;
    tile[r][c4 * 16 + z * 4 + 2] = v.z + u.z;
    tile[r][c4 * 16 + z * 4 + 3] = v.w + u.w;
  }
  __syncthreads();
  int d = t >> 2, sc = t & 3;
  u16* dst = vT + ((size_t)(h * 64 + d)) * S_LEN + s0 + sc * 16;
  unsigned wv[8];
#pragma unroll
  for (int z = 0; z < 8; ++z) {
    unsigned lo = f2bf(tile[sc * 16 + 2 * z][d]);
    unsigned hi = f2bf(tile[sc * 16 + 2 * z + 1][d]);
    wv[z] = lo | (hi << 16);
  }
  *reinterpret_cast<uint4*>(dst)     = make_uint4(wv[0], wv[1], wv[2], wv[3]);
  *reinterpret_cast<uint4*>(dst + 8) = make_uint4(wv[4], wv[5], wv[6], wv[7]);
}

// ---------------- flash attention: 4 waves/block, 16 q-rows/wave ----------------
__global__ __launch_bounds__(256) void attn_kernel(
    const u16* __restrict__ qro, const u16* __restrict__ kro,
    const u16* __restrict__ vT, u16* __restrict__ ctxb)
{
  __shared__ u16 plds[4][2][16 * 32];
  const int lane = threadIdx.x & 63;
  const int w = threadIdx.x >> 6;
  // XCD-chunked remap: same-head blocks land on the same XCD (K/V L2 locality)
  const int bid = (blockIdx.x & 7) * 64 + (blockIdx.x >> 3);   // 512 blocks, bijective
  const int h = bid >> 5;
  const int qt = (bid & 31) * 4 + w;     // 0..127
  const int lr = lane & 15, lg = lane >> 4;

  const u16* qbase = qro + ((size_t)(h * S_LEN + qt * 16 + lr)) * HD + lg * 8;
  bf16x8 qa0 = *reinterpret_cast<const bf16x8*>(qbase);
  bf16x8 qa1 = *reinterpret_cast<const bf16x8*>(qbase + 32);

  float mrow[4], lrow[4];
  f32x4 o[4];
#pragma unroll
  for (int j = 0; j < 4; ++j) { mrow[j] = -3.0e38f; lrow[j] = 0.f; }
#pragma unroll
  for (int n = 0; n < 4; ++n) o[n] = (f32x4){0.f, 0.f, 0.f, 0.f};

  for (int kt = 0; kt < 64; ++kt) {
    const int key0 = kt * 32;
    const u16* kb = kro + ((size_t)(h * S_LEN + key0 + lr)) * HD + lg * 8;
    bf16x8 k00 = *reinterpret_cast<const bf16x8*>(kb);
    bf16x8 k01 = *reinterpret_cast<const bf16x8*>(kb + 32);
    bf16x8 k10 = *reinterpret_cast<const bf16x8*>(kb + (size_t)16 * HD);
    bf16x8 k11 = *reinterpret_cast<const bf16x8*>(kb + (size_t)16 * HD + 32);

    f32x4 s0 = (f32x4){0.f, 0.f, 0.f, 0.f};
    f32x4 s1 = (f32x4){0.f, 0.f, 0.f, 0.f};
    __builtin_amdgcn_s_setprio(1);
    s0 = __builtin_amdgcn_mfma_f32_16x16x32_bf16(qa0, k00, s0, 0, 0, 0);
    s0 = __builtin_amdgcn_mfma_f32_16x16x32_bf16(qa1, k01, s0, 0, 0, 0);
    s1 = __builtin_amdgcn_mfma_f32_16x16x32_bf16(qa0, k10, s1, 0, 0, 0);
    s1 = __builtin_amdgcn_mfma_f32_16x16x32_bf16(qa1, k11, s1, 0, 0, 0);
    __builtin_amdgcn_s_setprio(0);

    float p0[4], p1[4], alpha[4];
#pragma unroll
    for (int j = 0; j < 4; ++j) {
      float v = fmaxf(s0[j], s1[j]);
      v = fmaxf(v, __shfl_xor(v, 1));
      v = fmaxf(v, __shfl_xor(v, 2));
      v = fmaxf(v, __shfl_xor(v, 4));
      v = fmaxf(v, __shfl_xor(v, 8));
      float mn = fmaxf(mrow[j], v);
      float al = __expf(mrow[j] - mn);
      float e0 = __expf(s0[j] - mn);
      float e1 = __expf(s1[j] - mn);
      lrow[j] = lrow[j] * al + e0 + e1;
      mrow[j] = mn;
      alpha[j] = al;
      p0[j] = e0; p1[j] = e1;
    }
#pragma unroll
    for (int n = 0; n < 4; ++n) {
#pragma unroll
      for (int j = 0; j < 4; ++j) o[n][j] *= alpha[j];
    }

    // per-wave private LDS round trip (wave-internal lgkmcnt ordering only)
    u16* pb = &plds[w][kt & 1][0];
#pragma unroll
    for (int j = 0; j < 4; ++j) {
      pb[(lg * 4 + j) * 32 + lr]      = f2bf(p0[j]);
      pb[(lg * 4 + j) * 32 + 16 + lr] = f2bf(p1[j]);
    }

    bf16x8 pa = *reinterpret_cast<const bf16x8*>(&pb[lr * 32 + lg * 8]);
    const u16* vb = vT + ((size_t)(h * 64 + lr)) * S_LEN + key0 + lg * 8;
    __builtin_amdgcn_s_setprio(1);
#pragma unroll
    for (int n = 0; n < 4; ++n) {
      bf16x8 vf = *reinterpret_cast<const bf16x8*>(vb + (size_t)(n * 16) * S_LEN);
      o[n] = __builtin_amdgcn_mfma_f32_16x16x32_bf16(pa, vf, o[n], 0, 0, 0);
    }
    __builtin_amdgcn_s_setprio(0);
  }

#pragma unroll
  for (int j = 0; j < 4; ++j) {
    float t = lrow[j];
    t += __shfl_xor(t, 1);
    t += __shfl_xor(t, 2);
    t += __shfl_xor(t, 4);
    t += __shfl_xor(t, 8);
    lrow[j] = 1.0f / t;
  }

#pragma unroll
  for (int n = 0; n < 4; ++n) {
    int col = h * 64 + n * 16 + lr;
#pragma unroll
    for (int j = 0; j < 4; ++j) {
      int row = qt * 16 + lg * 4 + j;
      ctxb[(size_t)row * HDIM + col] = f2bf(o[n][j] * lrow[j]);
    }
  }
}

extern "C" void kernel_launch(void* const* d_in, const int* in_sizes, int n_in,
                              void* d_out, int out_size, void* d_ws, size_t ws_size,
                              hipStream_t stream) {
  const float* x   = (const float*)d_in[0];
  const float* bw  = (const float*)d_in[1];
  const float* sw  = (const float*)d_in[2];
  const float* ssc = (const float*)d_in[3];
  const float* ow  = (const float*)d_in[4];
  const float* ob  = (const float*)d_in[5];
  const float* rc  = (const float*)d_in[6];
  const float* rs  = (const float*)d_in[7];
  float* out = (float*)d_out;

  char* ws = (char*)d_ws;
  u16*   Aaug  = (u16*)(ws);                        // 2048*9216*2  = 37,748,736
  u16*   Waug  = (u16*)(ws + 37748736);             // 3072*9216*2  = 56,623,104
  float* qkv0  = (float*)(ws + 94371840);           // 2048*3072*4  = 25,165,824
  float* qkv1  = (float*)(ws + 119537664);          // 25,165,824
  u16*   qro   = (u16*)(ws + 144703488);            // 16*2048*64*2 = 4,194,304
  u16*   kro   = (u16*)(ws + 148897792);            // 4,194,304
  u16*   vT    = (u16*)(ws + 153092096);            // 4,194,304
  u16*   owbf  = (u16*)(ws + 157286400);            // 1024*1024*2  = 2,097,152
  u16*   ctxb  = (u16*)(ws + 94371840);             // aliases qkv0 (dead after vtrans)
  // gemm2 partials: 4 x 2048*1024*4 = 33,554,432 over dead qkv1+qro+kro (ends at vT)
  float* part  = (float*)(ws + 119537664);

  prep_a_kernel<<<8192, 256, 0, stream>>>(x, Aaug);
  prep_w_kernel<<<12288, 256, 0, stream>>>(bw, sw, ssc, Waug);
  prep_ow_kernel<<<1024, 256, 0, stream>>>(ow, owbf);

  // KAN-linear GEMM, split-K=2: 768 blocks -> 3 blocks/CU
  gemm_bt<<<dim3(24, 16, 2), 256, 0, stream>>>(Aaug, Waug, qkv0, 2048, 3072, 9216, 4608);

  rope_kernel<<<4096, 256, 0, stream>>>(qkv0, qkv1, rc, rs, qro, kro);
  vtrans_kernel<<<512, 256, 0, stream>>>(qkv0, qkv1, vT);

  attn_kernel<<<512, 256, 0, stream>>>(qro, kro, vT, ctxb);

  // output projection, split-K=4 (512 blocks), then fused reduce+bias
  gemm_bt<<<dim3(8, 16, 4), 256, 0, stream>>>(ctxb, owbf, part, 2048, 1024, 1024, 256);
  reduce4_bias_kernel<<<2048, 256, 0, stream>>>(part, ob, out);
}

// Round 5
// 499.456 us; speedup vs baseline: 1.2522x; 1.0607x over previous
//
#include <hip/hip_runtime.h>

typedef unsigned short u16;
typedef __bf16 bf16x8 __attribute__((ext_vector_type(8)));
typedef float f32x4 __attribute__((ext_vector_type(4)));

#define S_LEN 2048
#define NHEADS 16
#define HD 64
#define HDIM 1024
#define QKVN 3072
#define KAUG 9216   // 1024 (silu) + 1024*8 (spline bases)

__device__ __forceinline__ u16 f2bf(float f) {
  union { float f; unsigned u; } v; v.f = f;
  unsigned r = v.u + 0x7fffu + ((v.u >> 16) & 1u);   // RNE
  return (u16)(r >> 16);
}

typedef __attribute__((address_space(1))) const unsigned int gas_u32;
typedef __attribute__((address_space(3))) unsigned int las_u32;
__device__ __forceinline__ void gload_lds16(const void* g, void* l) {
  __builtin_amdgcn_global_load_lds((gas_u32*)g, (las_u32*)l, 16, 0, 0);
}

// ---------------- prep A: silu(x) and cubic b-spline bases, bf16 ----------------
__global__ void prep_a_kernel(const float* __restrict__ x, u16* __restrict__ Aaug) {
  int idx = blockIdx.x * 256 + threadIdx.x;     // 2048*1024 threads
  int n = idx >> 10, i = idx & 1023;
  float xv = x[idx];
  float sil = xv / (1.0f + __expf(-xv));
  Aaug[(size_t)n * KAUG + i] = f2bf(sil);

  float b[11];
#pragma unroll
  for (int j = 0; j < 11; ++j) {
    float t0 = 0.4f * (float)(j - 3) - 1.0f;
    float t1 = 0.4f * (float)(j - 2) - 1.0f;
    b[j] = (xv >= t0 && xv < t1) ? 1.0f : 0.0f;
  }
  // recurrence with constant reciprocals (denominators are 0.4*k): no fdiv
#pragma unroll
  for (int k = 1; k <= 3; ++k) {
    const float invk = (k == 1) ? 2.5f : (k == 2) ? 1.25f : 0.83333333f;
#pragma unroll
    for (int j = 0; j < 10; ++j) {
      if (j + k < 11) {
        float tj   = 0.4f * (float)(j - 3) - 1.0f;
        float tjk1 = 0.4f * (float)(j + k - 2) - 1.0f;
        b[j] = ((xv - tj) * b[j] + (tjk1 - xv) * b[j + 1]) * invk;
      }
    }
  }
  u16 t[8];
#pragma unroll
  for (int j = 0; j < 8; ++j) t[j] = f2bf(b[j]);
  uint4 pk;
  pk.x = (unsigned)t[0] | ((unsigned)t[1] << 16);
  pk.y = (unsigned)t[2] | ((unsigned)t[3] << 16);
  pk.z = (unsigned)t[4] | ((unsigned)t[5] << 16);
  pk.w = (unsigned)t[6] | ((unsigned)t[7] << 16);
  *reinterpret_cast<uint4*>(&Aaug[(size_t)n * KAUG + 1024 + i * 8]) = pk;
}

// ---------------- prep W: [base_w | spline_w*scaler] bf16 ----------------
__global__ void prep_w_kernel(const float* __restrict__ bw, const float* __restrict__ sw,
                              const float* __restrict__ sc, u16* __restrict__ Waug) {
  int idx = blockIdx.x * 256 + threadIdx.x;     // 3072*1024 threads
  int o = idx >> 10, i = idx & 1023;
  Waug[(size_t)o * KAUG + i] = f2bf(bw[idx]);
  float s = sc[idx];
  const float4* sp = reinterpret_cast<const float4*>(sw + (size_t)idx * 8);
  float4 a = sp[0], b = sp[1];
  uint4 pk;
  pk.x = (unsigned)f2bf(a.x * s) | ((unsigned)f2bf(a.y * s) << 16);
  pk.y = (unsigned)f2bf(a.z * s) | ((unsigned)f2bf(a.w * s) << 16);
  pk.z = (unsigned)f2bf(b.x * s) | ((unsigned)f2bf(b.y * s) << 16);
  pk.w = (unsigned)f2bf(b.z * s) | ((unsigned)f2bf(b.w * s) << 16);
  *reinterpret_cast<uint4*>(&Waug[(size_t)o * KAUG + 1024 + i * 8]) = pk;
}

// ---------------- prep out_w -> bf16 ----------------
__global__ void prep_ow_kernel(const float* __restrict__ ow, u16* __restrict__ owbf) {
  int idx = blockIdx.x * 256 + threadIdx.x;     // 1024*1024/4 threads
  float4 v = reinterpret_cast<const float4*>(ow)[idx];
  uint2 pk;
  pk.x = (unsigned)f2bf(v.x) | ((unsigned)f2bf(v.y) << 16);
  pk.y = (unsigned)f2bf(v.z) | ((unsigned)f2bf(v.w) << 16);
  reinterpret_cast<uint2*>(owbf)[idx] = pk;
}

// ---------- GEMM: C[z][M,N] = A[M, kz] * B[N, kz]^T, bf16 MFMA, split-K via z ----------
// Round-3 measured-good structure: BK=32, 16KB LDS (revert of the r4 BK=64/32KB
// variant which halved occupancy and regressed 173->198us despite 0 bank conflicts).
__global__ __launch_bounds__(256) void gemm_bt(
    const u16* __restrict__ A, const u16* __restrict__ B, float* __restrict__ C,
    int M, int N, int K, int Ksp)
{
  __shared__ u16 As[128 * 32];
  __shared__ u16 Bs[128 * 32];
  const int tid = threadIdx.x;
  const int lane = tid & 63;
  const int w = tid >> 6;
  const int wr = w >> 1, wc = w & 1;
  const int row0 = blockIdx.y * 128, col0 = blockIdx.x * 128;
  const int lr = lane & 15, lg = lane >> 4;
  const int kbeg = blockIdx.z * Ksp;
  const int nsteps = Ksp >> 5;
  float* Cz = C + (size_t)blockIdx.z * M * N;

  f32x4 acc[4][4];
#pragma unroll
  for (int m = 0; m < 4; ++m)
#pragma unroll
    for (int n = 0; n < 4; ++n) acc[m][n] = (f32x4){0.f, 0.f, 0.f, 0.f};

  const int arow = tid >> 2;      // 0..63
  const int kch  = tid & 3;       // 0..3, 8 bf16 each
  const u16* ga = A + (size_t)(row0 + arow) * K + kbeg + kch * 8;
  const u16* gb = B + (size_t)(col0 + arow) * K + kbeg + kch * 8;
  const size_t rstep = (size_t)64 * K;

  for (int ks = 0; ks < nsteps; ++ks) {
    gload_lds16(ga, &As[tid * 8]);
    gload_lds16(ga + rstep, &As[2048 + tid * 8]);
    gload_lds16(gb, &Bs[tid * 8]);
    gload_lds16(gb + rstep, &Bs[2048 + tid * 8]);
    ga += 32; gb += 32;
    __syncthreads();

    bf16x8 af[4], bf[4];
#pragma unroll
    for (int m = 0; m < 4; ++m) {
      int r = wr * 64 + m * 16 + lr;
      af[m] = *reinterpret_cast<const bf16x8*>(&As[r * 32 + lg * 8]);
    }
#pragma unroll
    for (int n = 0; n < 4; ++n) {
      int r = wc * 64 + n * 16 + lr;
      bf[n] = *reinterpret_cast<const bf16x8*>(&Bs[r * 32 + lg * 8]);
    }
#pragma unroll
    for (int m = 0; m < 4; ++m)
#pragma unroll
      for (int n = 0; n < 4; ++n)
        acc[m][n] = __builtin_amdgcn_mfma_f32_16x16x32_bf16(af[m], bf[n], acc[m][n], 0, 0, 0);
    __syncthreads();
  }

#pragma unroll
  for (int m = 0; m < 4; ++m) {
    int row = row0 + wr * 64 + m * 16 + lg * 4;
#pragma unroll
    for (int n = 0; n < 4; ++n) {
      int col = col0 + wc * 64 + n * 16 + lr;
#pragma unroll
      for (int j = 0; j < 4; ++j)
        Cz[(size_t)(row + j) * N + col] = acc[m][n][j];
    }
  }
}

// ---------------- reduce 4 split-K partials + bias (float4) ----------------
__global__ void reduce4_bias_kernel(const float* __restrict__ p, const float* __restrict__ bias,
                                    float* __restrict__ out) {
  int idx = blockIdx.x * 256 + threadIdx.x;     // 2048*1024/4
  const float4* p4 = reinterpret_cast<const float4*>(p);
  const size_t stride4 = (size_t)2048 * 1024 / 4;
  float4 a = p4[idx], b = p4[idx + stride4], c = p4[idx + 2 * stride4], d = p4[idx + 3 * stride4];
  float4 bv = reinterpret_cast<const float4*>(bias)[idx & 255];
  float4 r;
  r.x = a.x + b.x + c.x + d.x + bv.x;
  r.y = a.y + b.y + c.y + d.y + bv.y;
  r.z = a.z + b.z + c.z + d.z + bv.z;
  r.w = a.w + b.w + c.w + d.w + bv.w;
  reinterpret_cast<float4*>(out)[idx] = r;
}

// ------- RoPE on q,k (sums the 2 split-K partials); per-head bf16, q scaled 1/8 -------
__global__ void rope_kernel(const float* __restrict__ qkv0, const float* __restrict__ qkv1,
                            const float* __restrict__ rc, const float* __restrict__ rs,
                            u16* __restrict__ qro, u16* __restrict__ kro) {
  int idx = blockIdx.x * 256 + threadIdx.x;   // 16*2048*32
  int h = idx >> 16;
  int rem = idx & 65535;
  int s = rem >> 5, i = rem & 31;
  size_t boff = (size_t)s * QKVN + h * 192 + 2 * i;
  float2 q0v = *reinterpret_cast<const float2*>(qkv0 + boff);
  float2 q1v = *reinterpret_cast<const float2*>(qkv1 + boff);
  float2 k0v = *reinterpret_cast<const float2*>(qkv0 + boff + 64);
  float2 k1v = *reinterpret_cast<const float2*>(qkv1 + boff + 64);
  float q0 = q0v.x + q1v.x, q1 = q0v.y + q1v.y;
  float k0 = k0v.x + k1v.x, k1 = k0v.y + k1v.y;
  float c = rc[s * 32 + i], sn = rs[s * 32 + i];
  size_t ob = ((size_t)(h * S_LEN + s)) * HD + 2 * i;
  unsigned qpk = (unsigned)f2bf((q0 * c - q1 * sn) * 0.125f) |
                 ((unsigned)f2bf((q0 * sn + q1 * c) * 0.125f) << 16);
  unsigned kpk = (unsigned)f2bf(k0 * c - k1 * sn) |
                 ((unsigned)f2bf(k0 * sn + k1 * c) << 16);
  *reinterpret_cast<unsigned*>(qro + ob) = qpk;
  *reinterpret_cast<unsigned*>(kro + ob) = kpk;
}

// ---------------- V transpose (sums 2 partials): vT[h][d][s] bf16 ----------------
__global__ void vtrans_kernel(const float* __restrict__ qkv0, const float* __restrict__ qkv1,
                              u16* __restrict__ vT) {
  __shared__ float tile[64][65];
  int h = blockIdx.x >> 5;
  int st = blockIdx.x & 31;
  int s0 = st * 64;
  int t = threadIdx.x;
  int r = t >> 2, c4 = t & 3;
  size_t soff = (size_t)(s0 + r) * QKVN + h * 192 + 128 + c4 * 16;
  const float* src0 = qkv0 + soff;
  const float* src1 = qkv1 + soff;
#pragma unroll
  for (int z = 0; z < 4; ++z) {
    float4 v = *reinterpret_cast<const float4*>(src0 + z * 4);
    float4 u = *reinterpret_cast<const float4*>(src1 + z * 4);
    tile[r][c4 * 16 + z * 4 + 0] = v.x + u.x;
    tile[r][c4 * 16 + z * 4 + 1] = v.y + u.y;
    tile[r][c4 * 16 + z * 4 + 2] = v.z + u.z;
    tile[r][c4 * 16 + z * 4 + 3] = v.w + u.w;
  }
  __syncthreads();
  int d = t >> 2, sc = t & 3;
  u16* dst = vT + ((size_t)(h * 64 + d)) * S_LEN + s0 + sc * 16;
  unsigned wv[8];
#pragma unroll
  for (int z = 0; z < 8; ++z) {
    unsigned lo = f2bf(tile[sc * 16 + 2 * z][d]);
    unsigned hi = f2bf(tile[sc * 16 + 2 * z + 1][d]);
    wv[z] = lo | (hi << 16);
  }
  *reinterpret_cast<uint4*>(dst)     = make_uint4(wv[0], wv[1], wv[2], wv[3]);
  *reinterpret_cast<uint4*>(dst + 8) = make_uint4(wv[4], wv[5], wv[6], wv[7]);
}

// ---- flash attention: swapped QK^T (S^T in regs), in-register softmax + P exchange ----
// Per wave: 16 q-rows. Lane (lr,lg) owns q-row lr; holds keys {4lg+j, 16+4lg+j} of S^T.
// m,l are per-lane scalars. P redistributed to the PV A-fragment via 8 shfl + 4 selects.
// Defer-max (T13, THR=8): O-rescale skipped unless wave votes max grew > 8.
__global__ __launch_bounds__(256) void attn_kernel(
    const u16* __restrict__ qro, const u16* __restrict__ kro,
    const u16* __restrict__ vT, u16* __restrict__ ctxb)
{
  const int lane = threadIdx.x & 63;
  const int w = threadIdx.x >> 6;
  // XCD-chunked remap: same-head blocks land on the same XCD (K/V L2 locality)
  const int bid = (blockIdx.x & 7) * 64 + (blockIdx.x >> 3);   // 512 blocks, bijective
  const int h = bid >> 5;
  const int qt = (bid & 31) * 4 + w;     // 0..127
  const int lr = lane & 15, lg = lane >> 4;

  const u16* qbase = qro + ((size_t)(h * S_LEN + qt * 16 + lr)) * HD + lg * 8;
  bf16x8 qa0 = *reinterpret_cast<const bf16x8*>(qbase);
  bf16x8 qa1 = *reinterpret_cast<const bf16x8*>(qbase + 32);

  float mrow = -3.0e38f, lrow = 0.f;
  f32x4 o[4];
#pragma unroll
  for (int n = 0; n < 4; ++n) o[n] = (f32x4){0.f, 0.f, 0.f, 0.f};

  const int sA = lr + 32 * (lg & 1);   // P-exchange source lanes
  const int sB = sA + 16;
  const bool loHalf = (lg < 2);

  for (int kt = 0; kt < 64; ++kt) {
    const int key0 = kt * 32;
    const u16* kb = kro + ((size_t)(h * S_LEN + key0 + lr)) * HD + lg * 8;
    bf16x8 k00 = *reinterpret_cast<const bf16x8*>(kb);
    bf16x8 k01 = *reinterpret_cast<const bf16x8*>(kb + 32);
    bf16x8 k10 = *reinterpret_cast<const bf16x8*>(kb + (size_t)16 * HD);
    bf16x8 k11 = *reinterpret_cast<const bf16x8*>(kb + (size_t)16 * HD + 32);

    // swapped QK^T: S^T tile; s0[j] = S[key0+4lg+j][q=lr], s1[j] = S[key0+16+4lg+j][q=lr]
    f32x4 s0 = (f32x4){0.f, 0.f, 0.f, 0.f};
    f32x4 s1 = (f32x4){0.f, 0.f, 0.f, 0.f};
    __builtin_amdgcn_s_setprio(1);
    s0 = __builtin_amdgcn_mfma_f32_16x16x32_bf16(k00, qa0, s0, 0, 0, 0);
    s0 = __builtin_amdgcn_mfma_f32_16x16x32_bf16(k01, qa1, s0, 0, 0, 0);
    s1 = __builtin_amdgcn_mfma_f32_16x16x32_bf16(k10, qa0, s1, 0, 0, 0);
    s1 = __builtin_amdgcn_mfma_f32_16x16x32_bf16(k11, qa1, s1, 0, 0, 0);
    __builtin_amdgcn_s_setprio(0);

    // row max over this lane's 8 keys, then across the 4 lg-groups of this q-row
    float vmax = fmaxf(fmaxf(fmaxf(s0[0], s0[1]), fmaxf(s0[2], s0[3])),
                       fmaxf(fmaxf(s1[0], s1[1]), fmaxf(s1[2], s1[3])));
    vmax = fmaxf(vmax, __shfl_xor(vmax, 16));
    vmax = fmaxf(vmax, __shfl_xor(vmax, 32));

    if (__any(vmax > mrow + 8.0f)) {       // defer-max: rare rescale
      float mnew = fmaxf(mrow, vmax);
      float al = __expf(mrow - mnew);
      float alO[4];
#pragma unroll
      for (int j = 0; j < 4; ++j) alO[j] = __shfl(al, lg * 4 + j);
#pragma unroll
      for (int n = 0; n < 4; ++n)
#pragma unroll
        for (int j = 0; j < 4; ++j) o[n][j] *= alO[j];
      lrow *= al;
      mrow = mnew;
    }

    float p[8];
#pragma unroll
    for (int j = 0; j < 4; ++j) {
      p[j]     = __expf(s0[j] - mrow);
      p[4 + j] = __expf(s1[j] - mrow);
    }
    lrow += ((p[0] + p[1]) + (p[2] + p[3])) + ((p[4] + p[5]) + (p[6] + p[7]));

    // pack to bf16: pu = {keys 4lg..+3, keys 16+4lg..+3}
    union { bf16x8 v; uint4 u; } pk_;
#pragma unroll
    for (int j = 0; j < 8; ++j) pk_.v[j] = (__bf16)p[j];

    // exchange: dest lane needs keys 8lg..8lg+7 of its q-row
    unsigned a0 = __shfl((int)pk_.u.x, sA), a1 = __shfl((int)pk_.u.y, sA);
    unsigned a2 = __shfl((int)pk_.u.x, sB), a3 = __shfl((int)pk_.u.y, sB);
    unsigned b0 = __shfl((int)pk_.u.z, sA), b1 = __shfl((int)pk_.u.w, sA);
    unsigned b2 = __shfl((int)pk_.u.z, sB), b3 = __shfl((int)pk_.u.w, sB);
    union { uint4 u; bf16x8 v; } pa_;
    pa_.u.x = loHalf ? a0 : b0;
    pa_.u.y = loHalf ? a1 : b1;
    pa_.u.z = loHalf ? a2 : b2;
    pa_.u.w = loHalf ? a3 : b3;

    const u16* vb = vT + ((size_t)(h * 64 + lr)) * S_LEN + key0 + lg * 8;
    __builtin_amdgcn_s_setprio(1);
#pragma unroll
    for (int n = 0; n < 4; ++n) {
      bf16x8 vf = *reinterpret_cast<const bf16x8*>(vb + (size_t)(n * 16) * S_LEN);
      o[n] = __builtin_amdgcn_mfma_f32_16x16x32_bf16(pa_.v, vf, o[n], 0, 0, 0);
    }
    __builtin_amdgcn_s_setprio(0);
  }

  // finish denominator: sum the 4 lg-partials of each q-row
  lrow += __shfl_xor(lrow, 16);
  lrow += __shfl_xor(lrow, 32);
  float linv[4];
#pragma unroll
  for (int j = 0; j < 4; ++j) linv[j] = 1.0f / __shfl(lrow, lg * 4 + j);

#pragma unroll
  for (int n = 0; n < 4; ++n) {
    int col = h * 64 + n * 16 + lr;
#pragma unroll
    for (int j = 0; j < 4; ++j) {
      int row = qt * 16 + lg * 4 + j;
      ctxb[(size_t)row * HDIM + col] = f2bf(o[n][j] * linv[j]);
    }
  }
}

extern "C" void kernel_launch(void* const* d_in, const int* in_sizes, int n_in,
                              void* d_out, int out_size, void* d_ws, size_t ws_size,
                              hipStream_t stream) {
  const float* x   = (const float*)d_in[0];
  const float* bw  = (const float*)d_in[1];
  const float* sw  = (const float*)d_in[2];
  const float* ssc = (const float*)d_in[3];
  const float* ow  = (const float*)d_in[4];
  const float* ob  = (const float*)d_in[5];
  const float* rc  = (const float*)d_in[6];
  const float* rs  = (const float*)d_in[7];
  float* out = (float*)d_out;

  char* ws = (char*)d_ws;
  u16*   Aaug  = (u16*)(ws);                        // 2048*9216*2  = 37,748,736
  u16*   Waug  = (u16*)(ws + 37748736);             // 3072*9216*2  = 56,623,104
  float* qkv0  = (float*)(ws + 94371840);           // 2048*3072*4  = 25,165,824
  float* qkv1  = (float*)(ws + 119537664);          // 25,165,824
  u16*   qro   = (u16*)(ws + 144703488);            // 16*2048*64*2 = 4,194,304
  u16*   kro   = (u16*)(ws + 148897792);            // 4,194,304
  u16*   vT    = (u16*)(ws + 153092096);            // 4,194,304
  u16*   owbf  = (u16*)(ws + 157286400);            // 1024*1024*2  = 2,097,152
  u16*   ctxb  = (u16*)(ws + 94371840);             // aliases qkv0 (dead after vtrans)
  // gemm2 partials: 4 x 2048*1024*4 = 33,554,432 over dead qkv1+qro+kro (ends at vT)
  float* part  = (float*)(ws + 119537664);

  prep_a_kernel<<<8192, 256, 0, stream>>>(x, Aaug);
  prep_w_kernel<<<12288, 256, 0, stream>>>(bw, sw, ssc, Waug);
  prep_ow_kernel<<<1024, 256, 0, stream>>>(ow, owbf);

  // KAN-linear GEMM, split-K=2: 768 blocks -> 3 blocks/CU
  gemm_bt<<<dim3(24, 16, 2), 256, 0, stream>>>(Aaug, Waug, qkv0, 2048, 3072, 9216, 4608);

  rope_kernel<<<4096, 256, 0, stream>>>(qkv0, qkv1, rc, rs, qro, kro);
  vtrans_kernel<<<512, 256, 0, stream>>>(qkv0, qkv1, vT);

  attn_kernel<<<512, 256, 0, stream>>>(qro, kro, vT, ctxb);

  // output projection, split-K=4 (512 blocks), then fused reduce+bias
  gemm_bt<<<dim3(8, 16, 4), 256, 0, stream>>>(ctxb, owbf, part, 2048, 1024, 1024, 256);
  reduce4_bias_kernel<<<2048, 256, 0, stream>>>(part, ob, out);
}